// Round 3
// baseline (1708.243 us; speedup 1.0000x reference)
//
#include <hip/hip_runtime.h>
#include <math.h>

// Residual SF-DiVeQ (N=65536, D=64, C=4, K=1024).
// ROUND 3: bit-exact emulation of the harness's float32 numpy reference.
//  - dot(rem, cb[k]) = sequential fmaf chain over d=0..63 (OpenBLAS sgemm
//    microkernel semantics: one accumulator per element, k ascending, FMA)
//  - row norms = numpy FLOAT_pairwise_sum for n=64: 8 accumulators stride-8,
//    then ((r0+r1)+(r2+r3))+((r4+r5)+(r6+r7))  (association fixed in numpy src)
//  - d2 = (srr - 2*dot) + cn with the reference's exact rounding order
//  - argmin strict < ascending (numpy first-index ties)
//  - rem chain in fp32 with single-rounded subtracts (matches scan carry)
//  - fp contraction OFF wherever bits matter; explicit fmaf where fusion needed
// z_q / perplexity epilogues stay fp64 (thresholds ~2% of magnitude; insensitive).

#define N_PTS 65536
#define DIM 64
#define NCB 4
#define KCB 1024

// ---------------- prep: cn[c][k] = numpy-pairwise ||c_k||^2 (fp32), zero counts
__global__ __launch_bounds__(256) void prep_kernel(const float* __restrict__ cb,
    float* __restrict__ cnp, int* __restrict__ counts)
{
#pragma clang fp contract(off)
    int t = blockIdx.x * 256 + threadIdx.x;       // grid 16 -> 4096 = C*K
    const float* row = cb + (size_t)t * DIM;
    float sq[DIM];
#pragma unroll
    for (int d = 0; d < DIM; ++d) { float v = row[d]; sq[d] = v * v; }
    float pr[8];
#pragma unroll
    for (int j = 0; j < 8; ++j) pr[j] = sq[j];
#pragma unroll
    for (int i = 8; i < DIM; i += 8)
#pragma unroll
        for (int j = 0; j < 8; ++j) pr[j] += sq[i + j];
    cnp[t] = ((pr[0] + pr[1]) + (pr[2] + pr[3])) + ((pr[4] + pr[5]) + (pr[6] + pr[7]));
    counts[t] = 0;
}

// ---------------- fused residual-VQ: all 4 codebooks, one thread per row -----
__global__ __launch_bounds__(256) void rvq_kernel(
    const float* __restrict__ z, const float* __restrict__ cbook,
    const float* __restrict__ cnp, int* __restrict__ idxA)
{
#pragma clang fp contract(off)
    int n = blockIdx.x * 256 + threadIdx.x;
    float rz[DIM];
    const float4* zr = (const float4*)(z + (size_t)n * DIM);
#pragma unroll
    for (int j = 0; j < DIM / 4; ++j) {
        float4 v = zr[j];
        rz[4*j+0] = v.x; rz[4*j+1] = v.y; rz[4*j+2] = v.z; rz[4*j+3] = v.w;
    }

    for (int c = 0; c < NCB; ++c) {
        // srr = numpy-pairwise sum of rz*rz (exact fp32 association)
        float sq[DIM];
#pragma unroll
        for (int d = 0; d < DIM; ++d) sq[d] = rz[d] * rz[d];
        float pr[8];
#pragma unroll
        for (int j = 0; j < 8; ++j) pr[j] = sq[j];
#pragma unroll
        for (int i = 8; i < DIM; i += 8)
#pragma unroll
            for (int j = 0; j < 8; ++j) pr[j] += sq[i + j];
        float srr = ((pr[0] + pr[1]) + (pr[2] + pr[3])) + ((pr[4] + pr[5]) + (pr[6] + pr[7]));

        const float* cb = cbook + (size_t)c * KCB * DIM;
        const float* cn = cnp + c * KCB;
        float m1 = 3.4028235e38f; int ix = 0;
        for (int k0 = 0; k0 < KCB; k0 += 8) {     // 8 k-chains in flight (ILP)
            float a[8];
#pragma unroll
            for (int j = 0; j < 8; ++j) a[j] = 0.0f;
#pragma unroll
            for (int d = 0; d < DIM; ++d) {       // d ASCENDING: sgemm k-chain order
#pragma unroll
                for (int j = 0; j < 8; ++j)
                    a[j] = fmaf(rz[d], cb[(size_t)(k0 + j) * DIM + d], a[j]);
            }
#pragma unroll
            for (int j = 0; j < 8; ++j) {         // ascending k: first-min wins
                float t1 = 2.0f * a[j];           // exact (x2)
                float t2 = srr - t1;              // one rounding (ref order)
                float dd = t2 + cn[k0 + j];       // one rounding (ref order)
                if (dd < m1) { m1 = dd; ix = k0 + j; }
            }
        }
        idxA[c * N_PTS + n] = ix;

        // rem = rem - cb[ix]  (single-rounded fp32, matches scan carry)
        const float4* q4 = (const float4*)(cb + (size_t)ix * DIM);
#pragma unroll
        for (int j = 0; j < DIM / 4; ++j) {
            float4 q = q4[j];
            rz[4*j+0] -= q.x; rz[4*j+1] -= q.y; rz[4*j+2] -= q.z; rz[4*j+3] -= q.w;
        }
    }
}

// ---------------- epilogue: z_q (fp64, insensitive to assoc; 2% threshold) ---
__global__ __launch_bounds__(256) void zq_kernel(
    const float* __restrict__ z, const float* __restrict__ noise,
    const float* __restrict__ cbase, const int* __restrict__ idxA,
    float* __restrict__ out)
{
    int lane = threadIdx.x & 63;
    int n = blockIdx.x * 4 + (threadIdx.x >> 6);   // grid 16384
    size_t e = (size_t)n * DIM + lane;
    double zd = z[e];
    double rd = zd;
#pragma unroll
    for (int cc = 0; cc < NCB; ++cc) {
        int id = idxA[cc * N_PTS + n];
        rd -= (double)cbase[((size_t)cc * KCB + id) * DIM + lane];
    }
    double dir = -rd;                               // z_hard - z
    double rv = fma(1e-3, (double)noise[e], dir);
    double srv = rv * rv, sdir = dir * dir;
#pragma unroll
    for (int off = 32; off >= 1; off >>= 1) {
        srv  += __shfl_xor(srv, off);
        sdir += __shfl_xor(sdir, off);
    }
    double em = sqrt(sdir);
    double nn = sqrt(srv); nn = nn > 1e-12 ? nn : 1e-12;
    out[e] = (float)(zd + em * rv / nn);
}

// ---------------- histogram + idx output (as float32) ------------------------
__global__ __launch_bounds__(256) void hist_kernel(
    const int* __restrict__ idxA, float* __restrict__ out_idx, int* __restrict__ counts)
{
    int t = blockIdx.x * 256 + threadIdx.x;        // C*N, grid 1024
    int v = idxA[t];
    out_idx[t] = (float)v;
    atomicAdd(&counts[(t >> 16) * KCB + v], 1);
}

// ---------------- perplexity -------------------------------------------------
__global__ __launch_bounds__(1024) void perp_kernel(const int* __restrict__ counts,
                                                    float* __restrict__ out)
{
    __shared__ double red[16];
    int tid = threadIdx.x, lane = tid & 63, w = tid >> 6;
    for (int c = 0; c < NCB; ++c) {
        double p = (double)counts[c * KCB + tid] / (double)N_PTS;
        double v = p * log(p + 1e-10);
#pragma unroll
        for (int off = 32; off >= 1; off >>= 1) v += __shfl_xor(v, off);
        if (lane == 0) red[w] = v;
        __syncthreads();
        if (tid == 0) {
            double ssum = 0.0;
            for (int i = 0; i < 16; ++i) ssum += red[i];
            out[c] = (float)exp(-ssum);
        }
        __syncthreads();
    }
}

extern "C" void kernel_launch(void* const* d_in, const int* in_sizes, int n_in,
                              void* d_out, int out_size, void* d_ws, size_t ws_size,
                              hipStream_t stream)
{
    const float* z     = (const float*)d_in[0];
    const float* cbook = (const float*)d_in[1];   // [C,K,D]
    const float* noise = (const float*)d_in[2];
    float* out = (float*)d_out;
    char* ws = (char*)d_ws;

    // ws layout (~1.1 MB)
    int*   idxA   = (int*)  (ws);                  // C*N i32   1,048,576 B
    float* cnp    = (float*)(ws + 1048576);        // C*K f32      16,384
    int*   counts = (int*)  (ws + 1064960);        // C*K i32      16,384

    prep_kernel<<<16, 256, 0, stream>>>(cbook, cnp, counts);
    rvq_kernel<<<N_PTS / 256, 256, 0, stream>>>(z, cbook, cnp, idxA);
    zq_kernel<<<N_PTS / 4, 256, 0, stream>>>(z, noise, cbook, idxA, out);
    hist_kernel<<<NCB * N_PTS / 256, 256, 0, stream>>>(
        idxA, out + (size_t)N_PTS * DIM, counts);
    perp_kernel<<<1, 1024, 0, stream>>>(
        counts, out + (size_t)N_PTS * DIM + (size_t)NCB * N_PTS);
}

// Round 4
// 682.340 us; speedup vs baseline: 2.5035x; 2.5035x over previous
//
#include <hip/hip_runtime.h>
#include <math.h>

// Residual SF-DiVeQ (N=65536, D=64, C=4, K=1024) — bit-exact numpy-fp32 argmin.
// R4: performance round.
//  - rvq: 8 waves/block, wave = K-partition (128 codewords), lane = row.
//    Grid 1024x512 (was 256x256, 12% occupancy). LDS merge of partial argmins
//    in ascending-k order with strict < (preserves numpy first-index ties).
//  - removed sq[64] temp (halves live registers; identical rounding:
//    pr[j] += rz*rz with contract off = one mul rounding + one add rounding).
//  - readfirstlane(wave) -> partition base provably SGPR-uniform -> s_load
//    for codebook rows (one scalar 32B load feeds 8 lanes' fmaf).
//  - __launch_bounds__(512,3): VGPR cap ~170 so rz[64] stays resident.

#define N_PTS 65536
#define DIM 64
#define NCB 4
#define KCB 1024
#define WAVES 8
#define KPART (KCB / WAVES)   // 128
#define ROWS_PER_BLK 64

// ---------------- prep: cn[c][k] = numpy-pairwise ||c_k||^2 (fp32), zero counts
__global__ __launch_bounds__(256) void prep_kernel(const float* __restrict__ cb,
    float* __restrict__ cnp, int* __restrict__ counts)
{
#pragma clang fp contract(off)
    int t = blockIdx.x * 256 + threadIdx.x;       // grid 16 -> 4096 = C*K
    const float* row = cb + (size_t)t * DIM;
    float pr[8];
#pragma unroll
    for (int j = 0; j < 8; ++j) { float v = row[j]; pr[j] = v * v; }
#pragma unroll
    for (int i = 8; i < DIM; i += 8)
#pragma unroll
        for (int j = 0; j < 8; ++j) { float v = row[i + j]; pr[j] += v * v; }
    cnp[t] = ((pr[0] + pr[1]) + (pr[2] + pr[3])) + ((pr[4] + pr[5]) + (pr[6] + pr[7]));
    counts[t] = 0;
}

// ---------------- fused residual-VQ ------------------------------------------
// block: 512 thr = 8 waves; wave w scans k in [w*128,(w+1)*128); lane = row.
__global__ __launch_bounds__(512, 3) void rvq_kernel(
    const float* __restrict__ z, const float* __restrict__ cbook,
    const float* __restrict__ cnp, int* __restrict__ idxA)
{
#pragma clang fp contract(off)
    __shared__ float lm[WAVES][ROWS_PER_BLK];
    __shared__ int   li[WAVES][ROWS_PER_BLK];

    int lane = threadIdx.x & 63;
    int w = __builtin_amdgcn_readfirstlane(threadIdx.x >> 6);  // SGPR-uniform
    int n = blockIdx.x * ROWS_PER_BLK + lane;
    int kbase = w * KPART;

    float rz[DIM];
    const float4* zr = (const float4*)(z + (size_t)n * DIM);
#pragma unroll
    for (int j = 0; j < DIM / 4; ++j) {
        float4 v = zr[j];
        rz[4*j+0] = v.x; rz[4*j+1] = v.y; rz[4*j+2] = v.z; rz[4*j+3] = v.w;
    }

    for (int c = 0; c < NCB; ++c) {
        // srr = numpy-pairwise sum of rz*rz (8 accumulators stride-8, fixed tree)
        float pr[8];
#pragma unroll
        for (int j = 0; j < 8; ++j) pr[j] = rz[j] * rz[j];
#pragma unroll
        for (int i = 8; i < DIM; i += 8)
#pragma unroll
            for (int j = 0; j < 8; ++j) pr[j] += rz[i + j] * rz[i + j];
        float srr = ((pr[0] + pr[1]) + (pr[2] + pr[3])) + ((pr[4] + pr[5]) + (pr[6] + pr[7]));

        const float* cb = cbook + (size_t)c * KCB * DIM;
        const float* cn = cnp + c * KCB;

        float m1 = 3.4028235e38f; int ix = kbase;
        for (int kk = 0; kk < KPART; kk += 8) {   // 8 sgemm-style k-chains
            int k0 = kbase + kk;
            float a[8];
#pragma unroll
            for (int j = 0; j < 8; ++j) a[j] = 0.0f;
#pragma unroll
            for (int d = 0; d < DIM; ++d) {       // d ascending: exact chain order
#pragma unroll
                for (int j = 0; j < 8; ++j)
                    a[j] = fmaf(rz[d], cb[(size_t)(k0 + j) * DIM + d], a[j]);
            }
#pragma unroll
            for (int j = 0; j < 8; ++j) {         // ascending k, strict <
                float t1 = 2.0f * a[j];           // exact
                float t2 = srr - t1;              // ref rounding order
                float dd = t2 + cn[k0 + j];
                if (dd < m1) { m1 = dd; ix = k0 + j; }
            }
        }
        lm[w][lane] = m1; li[w][lane] = ix;
        __syncthreads();

        // merge partitions in ascending w (= ascending k), strict <
        float bm = lm[0][lane]; int bx = li[0][lane];
#pragma unroll
        for (int s = 1; s < WAVES; ++s) {
            float v = lm[s][lane]; int xi = li[s][lane];
            if (v < bm) { bm = v; bx = xi; }
        }
        if (w == 0) idxA[c * N_PTS + n] = bx;

        // rem -= cb[bx]  (each wave updates its own copy; identical rounding)
        const float4* q4 = (const float4*)(cb + (size_t)bx * DIM);
#pragma unroll
        for (int j = 0; j < DIM / 4; ++j) {
            float4 q = q4[j];
            rz[4*j+0] -= q.x; rz[4*j+1] -= q.y; rz[4*j+2] -= q.z; rz[4*j+3] -= q.w;
        }
        __syncthreads();   // LDS reused next codebook
    }
}

// ---------------- epilogue: z_q (fp64; threshold ~2% of magnitude) -----------
__global__ __launch_bounds__(256) void zq_kernel(
    const float* __restrict__ z, const float* __restrict__ noise,
    const float* __restrict__ cbase, const int* __restrict__ idxA,
    float* __restrict__ out)
{
    int lane = threadIdx.x & 63;
    int n = blockIdx.x * 4 + (threadIdx.x >> 6);   // grid 16384
    size_t e = (size_t)n * DIM + lane;
    double zd = z[e];
    double rd = zd;
#pragma unroll
    for (int cc = 0; cc < NCB; ++cc) {
        int id = idxA[cc * N_PTS + n];
        rd -= (double)cbase[((size_t)cc * KCB + id) * DIM + lane];
    }
    double dir = -rd;                               // z_hard - z
    double rv = fma(1e-3, (double)noise[e], dir);
    double srv = rv * rv, sdir = dir * dir;
#pragma unroll
    for (int off = 32; off >= 1; off >>= 1) {
        srv  += __shfl_xor(srv, off);
        sdir += __shfl_xor(sdir, off);
    }
    double em = sqrt(sdir);
    double nn = sqrt(srv); nn = nn > 1e-12 ? nn : 1e-12;
    out[e] = (float)(zd + em * rv / nn);
}

// ---------------- histogram + idx output (as float32) ------------------------
__global__ __launch_bounds__(256) void hist_kernel(
    const int* __restrict__ idxA, float* __restrict__ out_idx, int* __restrict__ counts)
{
    int t = blockIdx.x * 256 + threadIdx.x;        // C*N, grid 1024
    int v = idxA[t];
    out_idx[t] = (float)v;
    atomicAdd(&counts[(t >> 16) * KCB + v], 1);
}

// ---------------- perplexity -------------------------------------------------
__global__ __launch_bounds__(1024) void perp_kernel(const int* __restrict__ counts,
                                                    float* __restrict__ out)
{
    __shared__ double red[16];
    int tid = threadIdx.x, lane = tid & 63, w = tid >> 6;
    for (int c = 0; c < NCB; ++c) {
        double p = (double)counts[c * KCB + tid] / (double)N_PTS;
        double v = p * log(p + 1e-10);
#pragma unroll
        for (int off = 32; off >= 1; off >>= 1) v += __shfl_xor(v, off);
        if (lane == 0) red[w] = v;
        __syncthreads();
        if (tid == 0) {
            double ssum = 0.0;
            for (int i = 0; i < 16; ++i) ssum += red[i];
            out[c] = (float)exp(-ssum);
        }
        __syncthreads();
    }
}

extern "C" void kernel_launch(void* const* d_in, const int* in_sizes, int n_in,
                              void* d_out, int out_size, void* d_ws, size_t ws_size,
                              hipStream_t stream)
{
    const float* z     = (const float*)d_in[0];
    const float* cbook = (const float*)d_in[1];   // [C,K,D]
    const float* noise = (const float*)d_in[2];
    float* out = (float*)d_out;
    char* ws = (char*)d_ws;

    // ws layout (~1.1 MB)
    int*   idxA   = (int*)  (ws);                  // C*N i32   1,048,576 B
    float* cnp    = (float*)(ws + 1048576);        // C*K f32      16,384
    int*   counts = (int*)  (ws + 1064960);        // C*K i32      16,384

    prep_kernel<<<16, 256, 0, stream>>>(cbook, cnp, counts);
    rvq_kernel<<<N_PTS / ROWS_PER_BLK, 512, 0, stream>>>(z, cbook, cnp, idxA);
    zq_kernel<<<N_PTS / 4, 256, 0, stream>>>(z, noise, cbook, idxA, out);
    hist_kernel<<<NCB * N_PTS / 256, 256, 0, stream>>>(
        idxA, out + (size_t)N_PTS * DIM, counts);
    perp_kernel<<<1, 1024, 0, stream>>>(
        counts, out + (size_t)N_PTS * DIM + (size_t)NCB * N_PTS);
}